// Round 1
// baseline (309.870 us; speedup 1.0000x reference)
//
#include <hip/hip_runtime.h>
#include <math.h>

typedef unsigned int u32;

#define HH 256
#define WW 256
#define IMG 65536
#define PER_BATCH 196608
#define NB 32
#define TOTAL 6291456
#define NCELL 4900   // 70*70 halo region (64 tile + 2*3 halo)

__device__ __forceinline__ float med3f(float a, float b, float c) {
    return fmaxf(fminf(a, b), fminf(fmaxf(a, b), c));
}
__device__ __forceinline__ float med5f(float a0, float a1, float a2, float a3, float a4) {
    float mn01 = fminf(a0, a1), mx01 = fmaxf(a0, a1);
    float mn34 = fminf(a3, a4), mx34 = fmaxf(a3, a4);
    return med3f(a2, fmaxf(mn01, mn34), fminf(mx01, mx34));
}

// ---------------- median (radix select) ----------------

__global__ void init_kernel(u32* __restrict__ gh, u32* __restrict__ prefix,
                            u32* __restrict__ kk, float* __restrict__ madsum) {
    int t = blockIdx.x * 256 + threadIdx.x;
    if (t < 8192) gh[t] = 0u;
    if (t < NB) { prefix[t] = 0u; kk[t] = 98303u; }   // (196608-1)/2 lower median rank
    if (t == 0) *madsum = 0.0f;
}

__global__ void hist_kernel(const float* __restrict__ x, u32* __restrict__ gh,
                            const u32* __restrict__ prefix, int byteIdx) {
    __shared__ u32 lh[2048];   // 256 bins x 8 lane-spread sub-bins
    int b = blockIdx.x / 24;
    int s = blockIdx.x % 24;
    int tid = threadIdx.x;
    for (int i = tid; i < 2048; i += 256) lh[i] = 0u;
    __syncthreads();
    u32 pref = prefix[b];
    int lane8 = tid & 7;
    const float* xb = x + (size_t)b * PER_BATCH + (size_t)s * 8192;
    #pragma unroll 4
    for (int i = 0; i < 32; ++i) {
        u32 bits = __float_as_uint(fabsf(xb[tid + i * 256]));
        u32 hi = (byteIdx == 3) ? 0u : (bits >> ((byteIdx + 1) * 8));
        bool ok = (byteIdx == 3) || (hi == pref);
        if (ok) atomicAdd(&lh[(((bits >> (byteIdx * 8)) & 255u) << 3) + lane8], 1u);
    }
    __syncthreads();
    u32 ssum = 0;
    #pragma unroll
    for (int j = 0; j < 8; ++j) ssum += lh[(tid << 3) + j];
    if (ssum) atomicAdd(&gh[b * 256 + tid], ssum);
}

__global__ void select_kernel(u32* __restrict__ gh, u32* __restrict__ prefix,
                              u32* __restrict__ kk, float* __restrict__ scale, int byteIdx) {
    __shared__ u32 sh[256];
    int b = blockIdx.x;
    int t = threadIdx.x;
    sh[t] = gh[b * 256 + t];
    gh[b * 256 + t] = 0u;   // zero for next pass
    __syncthreads();
    if (t == 0) {
        u32 k = kk[b];
        int bucket = 255;
        for (int j = 0; j < 256; ++j) {
            u32 c = sh[j];
            if (k < c) { bucket = j; break; }
            k -= c;
        }
        kk[b] = k;
        u32 p = (prefix[b] << 8) | (u32)bucket;
        prefix[b] = p;
        if (byteIdx == 0) scale[b] = __uint_as_float(p) + 1e-8f;
    }
}

// ---------------- denoise (4 Huber-TV views, 3 iters, tiled in LDS) ----------------

__launch_bounds__(256, 3)
__global__ void denoise_kernel(const float* __restrict__ x, const float* __restrict__ scale,
                               float* __restrict__ arts, float* __restrict__ madsum,
                               float4 lam4, float4 del4) {
    __shared__ float s_xn[NCELL];
    __shared__ float s_xd[NCELL];
    __shared__ float red[4];
    int bid = blockIdx.x;
    int img = bid >> 4;                 // 96 images (b*3+c)
    int tl = bid & 15;
    int tY = (tl >> 2) * 64 - 3;        // global row of halo-region origin
    int tX = (tl & 3) * 64 - 3;
    int b = img / 3;
    float sc = scale[b];
    float inv_sc = 1.0f / sc;
    const float* xi = x + (size_t)img * IMG;
    int tid = threadIdx.x;

    // load halo region, normalized
    #pragma unroll
    for (int j = 0; j < 20; ++j) {
        int idx = tid + j * 256;
        if (idx < NCELL) {
            int ly = idx / 70, lx = idx - ly * 70;
            int gy = tY + ly, gx = tX + lx;
            float v = 0.0f;
            if ((u32)gy < 256u && (u32)gx < 256u) v = xi[gy * 256 + gx] * inv_sc;
            s_xn[idx] = v;
        }
    }

    const float lams[4] = {lam4.x, lam4.y, lam4.z, lam4.w};
    const float dels[4] = {del4.x, del4.y, del4.z, del4.w};
    float art[4][16];

    #pragma unroll
    for (int v = 0; v < 4; ++v) {
        __syncthreads();   // protect s_xd from prior view's readers
        #pragma unroll
        for (int j = 0; j < 20; ++j) {
            int idx = tid + j * 256;
            if (idx < NCELL) s_xd[idx] = s_xn[idx];
        }
        __syncthreads();
        float lam = lams[v], del = dels[v];
        #pragma unroll 1
        for (int k = 0; k < 3; ++k) {
            float nv[20];
            #pragma unroll
            for (int j = 0; j < 20; ++j) {
                int idx = tid + j * 256;
                nv[j] = 0.0f;
                if (idx < NCELL) {
                    int ly = idx / 70, lx = idx - ly * 70;
                    int gy = tY + ly, gx = tX + lx;
                    float c = s_xd[idx];
                    nv[j] = c;   // default: keep old value
                    if ((u32)gy < 256u && (u32)gx < 256u &&
                        ly >= k + 1 && ly <= 68 - k && lx >= k + 1 && lx <= 68 - k) {
                        float gxc = 0.f, gxl = 0.f, gyc = 0.f, gyl = 0.f;
                        if (gx < 255) { float d = s_xd[idx + 1] - c;  gxc = d * __builtin_amdgcn_rcpf(del + fabsf(d)); }
                        if (gx > 0)   { float d = c - s_xd[idx - 1];  gxl = d * __builtin_amdgcn_rcpf(del + fabsf(d)); }
                        if (gy < 255) { float d = s_xd[idx + 70] - c; gyc = d * __builtin_amdgcn_rcpf(del + fabsf(d)); }
                        if (gy > 0)   { float d = c - s_xd[idx - 70]; gyl = d * __builtin_amdgcn_rcpf(del + fabsf(d)); }
                        float dv = (gxc - gxl) + (gyc - gyl);
                        nv[j] = c - 0.2f * (c - s_xn[idx] - lam * dv);
                    }
                }
            }
            __syncthreads();
            #pragma unroll
            for (int j = 0; j < 20; ++j) {
                int idx = tid + j * 256;
                if (idx < NCELL) s_xd[idx] = nv[j];
            }
            __syncthreads();
        }
        // extract interior (64x64), scaled back
        #pragma unroll
        for (int j2 = 0; j2 < 16; ++j2) {
            int ii = tid + j2 * 256;
            int r = ii >> 6, cl = ii & 63;
            art[v][j2] = s_xd[(r + 3) * 70 + (cl + 3)] * sc;
        }
    }

    // write art planes + accumulate mad for global mean
    float msum = 0.0f;
    int gy0 = tY + 3, gx0 = tX + 3;
    #pragma unroll
    for (int j2 = 0; j2 < 16; ++j2) {
        int ii = tid + j2 * 256;
        int r = ii >> 6, cl = ii & 63;
        size_t e = (size_t)img * IMG + (size_t)(gy0 + r) * 256 + (gx0 + cl);
        float a1 = art[0][j2], a2 = art[1][j2], a3 = art[2][j2], a4 = art[3][j2];
        arts[e] = a1;
        arts[(size_t)TOTAL + e] = a2;
        arts[2 * (size_t)TOTAL + e] = a3;
        arts[3 * (size_t)TOTAL + e] = a4;
        float a0 = s_xn[(r + 3) * 70 + (cl + 3)] * sc;
        float med = med5f(a0, a1, a2, a3, a4);
        float mad = med5f(fabsf(a0 - med), fabsf(a1 - med), fabsf(a2 - med),
                          fabsf(a3 - med), fabsf(a4 - med));
        msum += mad;
    }
    #pragma unroll
    for (int off = 32; off > 0; off >>= 1) msum += __shfl_down(msum, off);
    if ((tid & 63) == 0) red[tid >> 6] = msum;
    __syncthreads();
    if (tid == 0) atomicAdd(madsum, red[0] + red[1] + red[2] + red[3]);
}

// ---------------- fusion ----------------

__global__ void fuse_kernel(const float* __restrict__ x, const float* __restrict__ arts,
                            const float* __restrict__ madsum, float* __restrict__ out) {
    size_t i4 = ((size_t)blockIdx.x * 256 + threadIdx.x) * 4;
    float floorv = 0.1f * (*madsum) * (1.0f / 6291456.0f);
    float4 v0 = *(const float4*)(x + i4);
    float4 v1 = *(const float4*)(arts + i4);
    float4 v2 = *(const float4*)(arts + (size_t)TOTAL + i4);
    float4 v3 = *(const float4*)(arts + 2 * (size_t)TOTAL + i4);
    float4 v4 = *(const float4*)(arts + 3 * (size_t)TOTAL + i4);
    float4 o;
#define FUSE1(c) { \
        float a0 = v0.c, a1 = v1.c, a2 = v2.c, a3 = v3.c, a4 = v4.c; \
        float med = med5f(a0, a1, a2, a3, a4); \
        float d0 = fabsf(a0 - med), d1 = fabsf(a1 - med), d2 = fabsf(a2 - med); \
        float d3 = fabsf(a3 - med), d4 = fabsf(a4 - med); \
        float mad = med5f(d0, d1, d2, d3, d4); \
        float m = fmaxf(mad, floorv); \
        float inv = 1.0f / (2.0f * m); \
        float w0 = __expf(-d0 * inv), w1 = __expf(-d1 * inv), w2 = __expf(-d2 * inv); \
        float w3 = __expf(-d3 * inv), w4 = __expf(-d4 * inv); \
        float swt = w0 + w1 + w2 + w3 + w4; \
        float sva = w0 * a0 + w1 * a1 + w2 * a2 + w3 * a3 + w4 * a4; \
        o.c = sva / (swt + 1e-8f); \
    }
    FUSE1(x); FUSE1(y); FUSE1(z); FUSE1(w);
#undef FUSE1
    *(float4*)(out + i4) = o;
}

// ---------------- launch ----------------

extern "C" void kernel_launch(void* const* d_in, const int* in_sizes, int n_in,
                              void* d_out, int out_size, void* d_ws, size_t ws_size,
                              hipStream_t stream) {
    const float* x = (const float*)d_in[0];
    float* out = (float*)d_out;
    char* ws = (char*)d_ws;
    float* madsum = (float*)ws;                 // 4 B
    u32* prefix   = (u32*)(ws + 8);             // 32
    u32* kk       = (u32*)(ws + 8 + 128);       // 32
    float* scale  = (float*)(ws + 8 + 256);     // 32
    u32* gh       = (u32*)(ws + 512);           // 32*256 u32 = 32 KB
    float* arts   = (float*)(ws + 65536);       // 4 planes * 24 MB

    init_kernel<<<32, 256, 0, stream>>>(gh, prefix, kk, madsum);
    for (int byteIdx = 3; byteIdx >= 0; --byteIdx) {
        hist_kernel<<<768, 256, 0, stream>>>(x, gh, prefix, byteIdx);
        select_kernel<<<32, 256, 0, stream>>>(gh, prefix, kk, scale, byteIdx);
    }

    // deterministic param sets (match reference: double math, cast to f32)
    float lamf[4], delf[4];
    for (int i = 0; i < 4; ++i) {
        double lam = 0.025 + 0.05 * (double)i / 3.0;
        lamf[i] = (float)lam;
        delf[i] = (float)(0.01 * sqrt(lam / (0.05 + 1e-8)));
    }
    float4 lam4 = make_float4(lamf[0], lamf[1], lamf[2], lamf[3]);
    float4 del4 = make_float4(delf[0], delf[1], delf[2], delf[3]);

    denoise_kernel<<<1536, 256, 0, stream>>>(x, scale, arts, madsum, lam4, del4);
    fuse_kernel<<<6144, 256, 0, stream>>>(x, arts, madsum, out);
}

// Round 2
// 251.285 us; speedup vs baseline: 1.2331x; 1.2331x over previous
//
#include <hip/hip_runtime.h>
#include <math.h>

typedef unsigned int u32;

#define TOTALPIX 6291456

__device__ __forceinline__ float med3f(float a, float b, float c) {
    return fmaxf(fminf(a, b), fminf(fmaxf(a, b), c));
}
__device__ __forceinline__ float med5f(float a0, float a1, float a2, float a3, float a4) {
    float mn01 = fminf(a0, a1), mx01 = fmaxf(a0, a1);
    float mn34 = fminf(a3, a4), mx34 = fmaxf(a3, a4);
    return med3f(a2, fmaxf(mn01, mn34), fminf(mx01, mx34));
}
__device__ __forceinline__ u32 packbf(float lo, float hi) {
    u32 a = __float_as_uint(lo), b = __float_as_uint(hi);
    a = (a + 0x7FFFu + ((a >> 16) & 1u)) >> 16;
    b = (b + 0x7FFFu + ((b >> 16) & 1u)) >> 16;
    return a | (b << 16);
}

// ---------------- init ----------------

__global__ void init_kernel(u32* __restrict__ gh, u32* __restrict__ prefix,
                            u32* __restrict__ kk, u32* __restrict__ done,
                            float* __restrict__ madsum) {
    int t = blockIdx.x * 256 + threadIdx.x;
    if (t < 8192) gh[t] = 0u;
    if (t < 128) done[t] = 0u;
    if (t < 32) { prefix[t] = 0u; kk[t] = 98303u; }  // (196608-1)/2 lower-median rank
    if (t == 0) *madsum = 0.0f;
}

// ---------------- fused histogram + last-block radix select ----------------

__global__ __launch_bounds__(256) void hist_kernel(
        const float* __restrict__ x, u32* __restrict__ gh, u32* __restrict__ prefix,
        u32* __restrict__ kk, float* __restrict__ scale, u32* __restrict__ done,
        int byteIdx) {
    __shared__ u32 lh[16384];   // 256 bins x 64 lane slots: zero atomic contention
    __shared__ int amLast;
    __shared__ u32 wtot[4];
    int b = blockIdx.x / 24, s = blockIdx.x % 24;
    int tid = threadIdx.x, lane = tid & 63, wid = tid >> 6;
    uint4 z = make_uint4(0u, 0u, 0u, 0u);
    #pragma unroll
    for (int j = 0; j < 16; ++j) ((uint4*)lh)[tid + j * 256] = z;
    __syncthreads();
    u32 pref = prefix[b];
    const float4* xb = (const float4*)(x + (size_t)b * 196608 + (size_t)s * 8192);
    int shl = byteIdx * 8;
    #pragma unroll
    for (int j = 0; j < 8; ++j) {
        float4 v = xb[tid + j * 256];
        float vv[4] = {v.x, v.y, v.z, v.w};
        #pragma unroll
        for (int e = 0; e < 4; ++e) {
            u32 bits = __float_as_uint(fabsf(vv[e]));
            bool ok = (byteIdx == 3) || ((bits >> (shl + 8)) == pref);
            if (ok) atomicAdd(&lh[(((bits >> shl) & 255u) << 6) + lane], 1u);
        }
    }
    __syncthreads();
    u32 sum = 0;
    #pragma unroll
    for (int j = 0; j < 64; ++j) sum += lh[(tid << 6) + ((j + lane) & 63)];  // staggered: no bank conflicts
    if (sum) atomicAdd(&gh[b * 256 + tid], sum);
    __syncthreads();
    if (tid == 0) {
        __threadfence();
        amLast = (atomicAdd(&done[byteIdx * 32 + b], 1u) == 23u);
    }
    __syncthreads();
    if (!amLast) return;
    // last block for this batch: select the bucket containing rank kk[b]
    u32 cnt = __hip_atomic_load(&gh[b * 256 + tid], __ATOMIC_RELAXED, __HIP_MEMORY_SCOPE_AGENT);
    gh[b * 256 + tid] = 0u;   // ready for next pass (visible at dispatch boundary)
    u32 inc = cnt;
    #pragma unroll
    for (int off = 1; off < 64; off <<= 1) {
        u32 o = __shfl_up(inc, off);
        if (lane >= off) inc += o;
    }
    if (lane == 63) wtot[wid] = inc;
    __syncthreads();
    u32 add = 0;
    for (int w = 0; w < 4; ++w) if (w < wid) add += wtot[w];
    inc += add;
    u32 exc = inc - cnt;
    u32 k = kk[b];
    if (exc <= k && k < inc) {   // exactly one thread matches
        kk[b] = k - exc;
        u32 p = (pref << 8) | (u32)tid;
        prefix[b] = p;
        if (byteIdx == 0) scale[b] = __uint_as_float(p) + 1e-8f;
    }
}

// ---------------- denoise: register-pipelined row sweep ----------------
// lanes = 64 cols (coalesced), sweep rows; 3 Jacobi stages pipelined (stage k
// at step r computes row r-k); 4 views in flight. No LDS. 2 rcps per cell.

__device__ __forceinline__ float stageu(float B, float C, float xnB, float& gyp,
                                        int row, float mR, float mL, float lam, float del) {
    float dy = C - B;                                     // X[row+1]-X[row]; pad->0 at row 255
    float gy = dy * __builtin_amdgcn_rcpf(del + fabsf(dy));
    if (row >= 255) gy = 0.0f;                            // uniform branch
    float divy = gy - ((row == 0) ? 0.0f : gyp);          // div_y[0] = gy[0]
    gyp = gy;
    float Bn = __shfl_down(B, 1);                         // col c+1
    float dx = Bn - B;
    float gx = dx * __builtin_amdgcn_rcpf(del + fabsf(dx));
    gx *= mR;                                             // gx=0 at col 255
    float gxU = __shfl_up(gx, 1) * mL;                    // div_x[0] = gx[0]
    float t = B - xnB;
    t = fmaf(-lam, (gx - gxU) + divy, t);
    return fmaf(-0.2f, t, B);
}

__global__ __launch_bounds__(256, 4) void denoise_kernel(
        const float* __restrict__ x, const float* __restrict__ scale,
        uint2* __restrict__ arts, float* __restrict__ madsum,
        float4 lam4, float4 del4) {
    int bid = blockIdx.x;
    int img = bid / 10;            // 96 images (b*3+c)
    int r10 = bid % 10;
    int band = r10 >> 1;           // 5 column bands
    int q = r10 & 1;
    int tid = threadIdx.x;
    int lane = tid & 63;
    int wid = tid >> 6;
    int seg = q * 4 + wid;         // 8 row segments of 32 rows
    int cb = (band == 4) ? 192 : band * 58;
    int wlo = (band == 0) ? 0 : band * 58 + 3;
    int whi = (band == 4) ? 255 : band * 58 + 60;
    int c = cb + lane;
    bool act = (c >= wlo) && (c <= whi);
    float mR = (c == 255) ? 0.0f : 1.0f;
    float mL = (c == 0) ? 0.0f : 1.0f;
    float sc = scale[img / 3];
    float inv_sc = 1.0f / sc;
    const float* xp = x + (size_t)img * 65536 + c;
    uint2* ap = arts + (size_t)img * 65536 + c;

    float lam[4] = {lam4.x, lam4.y, lam4.z, lam4.w};
    float del[4] = {del4.x, del4.y, del4.z, del4.w};
    float cur1[4], cur2[4], gyp1[4], gyp2[4], gyp3[4];
    #pragma unroll
    for (int v = 0; v < 4; ++v) { cur1[v] = 0.f; cur2[v] = 0.f; gyp1[v] = 0.f; gyp2[v] = 0.f; gyp3[v] = 0.f; }
    float n0 = 0.f, n1 = 0.f, n2 = 0.f;
    int out_lo = seg * 32, out_hi = out_lo + 31;
    int rs = (out_lo >= 3) ? out_lo - 3 : 0;   // 3-row pipeline warm-up
    int rend = out_hi + 3;                      // 3-step flush
    float msum = 0.0f;

    float nl = (rs <= 255) ? xp[rs << 8] * inv_sc : 0.0f;
    for (int r = rs; r <= rend; ++r) {
        float nxt = 0.0f;
        if (r < rend && (r + 1) <= 255) nxt = xp[(r + 1) << 8];   // prefetch
        int r1 = r - 1, r2 = r - 2, r3 = r - 3;
        float a[4];
        #pragma unroll
        for (int v = 0; v < 4; ++v) {
            float x1 = stageu(n0,      nl, n0, gyp1[v], r1, mR, mL, lam[v], del[v]);
            float x2 = stageu(cur1[v], x1, n1, gyp2[v], r2, mR, mL, lam[v], del[v]);
            float x3 = stageu(cur2[v], x2, n2, gyp3[v], r3, mR, mL, lam[v], del[v]);
            cur1[v] = x1; cur2[v] = x2; a[v] = x3;
        }
        if (r3 >= out_lo) {   // uniform; r3 <= out_hi by loop bound
            float a1 = a[0] * sc, a2 = a[1] * sc, a3 = a[2] * sc, a4 = a[3] * sc;
            float a0 = n2 * sc;
            if (act) {
                uint2 pk;
                pk.x = packbf(a1, a2);
                pk.y = packbf(a3, a4);
                ap[r3 << 8] = pk;
                float med = med5f(a0, a1, a2, a3, a4);
                float mad = med5f(fabsf(a0 - med), fabsf(a1 - med), fabsf(a2 - med),
                                  fabsf(a3 - med), fabsf(a4 - med));
                msum += mad;
            }
        }
        n2 = n1; n1 = n0; n0 = nl;
        nl = nxt * inv_sc;
    }
    #pragma unroll
    for (int off = 32; off > 0; off >>= 1) msum += __shfl_down(msum, off);
    if (lane == 0) atomicAdd(madsum, msum);
}

// ---------------- fusion ----------------

__global__ __launch_bounds__(256) void fuse_kernel(
        const float* __restrict__ x, const uint2* __restrict__ arts,
        const float* __restrict__ madsum, float* __restrict__ out) {
    int i = blockIdx.x * 256 + threadIdx.x;
    float floorv = 0.1f * (*madsum) * (1.0f / 6291456.0f);
    uint2 pk = arts[i];
    float a0 = x[i];
    float a1 = __uint_as_float(pk.x << 16);
    float a2 = __uint_as_float(pk.x & 0xFFFF0000u);
    float a3 = __uint_as_float(pk.y << 16);
    float a4 = __uint_as_float(pk.y & 0xFFFF0000u);
    float med = med5f(a0, a1, a2, a3, a4);
    float d0 = fabsf(a0 - med), d1 = fabsf(a1 - med), d2 = fabsf(a2 - med);
    float d3 = fabsf(a3 - med), d4 = fabsf(a4 - med);
    float mad = med5f(d0, d1, d2, d3, d4);
    float m = fmaxf(mad, floorv);
    float inv = 0.5f / m;
    float w0 = __expf(-d0 * inv), w1 = __expf(-d1 * inv), w2 = __expf(-d2 * inv);
    float w3 = __expf(-d3 * inv), w4 = __expf(-d4 * inv);
    float swt = w0 + w1 + w2 + w3 + w4;
    float sva = fmaf(w0, a0, fmaf(w1, a1, fmaf(w2, a2, fmaf(w3, a3, w4 * a4))));
    out[i] = sva / (swt + 1e-8f);
}

// ---------------- launch ----------------

extern "C" void kernel_launch(void* const* d_in, const int* in_sizes, int n_in,
                              void* d_out, int out_size, void* d_ws, size_t ws_size,
                              hipStream_t stream) {
    const float* x = (const float*)d_in[0];
    float* out = (float*)d_out;
    char* ws = (char*)d_ws;
    float* madsum = (float*)ws;                  // 4 B
    u32* prefix   = (u32*)(ws + 128);            // 32
    u32* kk       = (u32*)(ws + 256);            // 32
    float* scale  = (float*)(ws + 384);          // 32
    u32* done     = (u32*)(ws + 512);            // 128
    u32* gh       = (u32*)(ws + 1024);           // 32*256 u32 = 32 KB
    uint2* arts   = (uint2*)(ws + 65536);        // 6.29M * 8 B = 50.3 MB

    init_kernel<<<32, 256, 0, stream>>>(gh, prefix, kk, done, madsum);
    for (int byteIdx = 3; byteIdx >= 0; --byteIdx) {
        hist_kernel<<<768, 256, 0, stream>>>(x, gh, prefix, kk, scale, done, byteIdx);
    }

    float lamf[4], delf[4];
    for (int i = 0; i < 4; ++i) {
        double lam = 0.025 + 0.05 * (double)i / 3.0;
        lamf[i] = (float)lam;
        delf[i] = (float)(0.01 * sqrt(lam / (0.05 + 1e-8)));
    }
    float4 lam4 = make_float4(lamf[0], lamf[1], lamf[2], lamf[3]);
    float4 del4 = make_float4(delf[0], delf[1], delf[2], delf[3]);

    denoise_kernel<<<960, 256, 0, stream>>>(x, scale, arts, madsum, lam4, del4);
    fuse_kernel<<<24576, 256, 0, stream>>>(x, arts, madsum, out);
}